// Round 1
// baseline (101.906 us; speedup 1.0000x reference)
//
#include <hip/hip_runtime.h>
#include <math.h>
#include <float.h>

// Problem constants (B=4, S=1024, V=32000), T = S-1 = 1023 scored tokens.
#define BATCH 4
#define SEQ   1024
#define TT    1023
#define VOC   32000
#define VOC4  (VOC / 4)   // 8000 float4 per row

// Kernel 1: one block (256 threads) per (b, t) row.
// Computes online logsumexp + entropy moment in a single streaming pass.
//   m  = running max
//   s0 = sum exp(l - m)
//   s1 = sum exp(l - m) * l
//   lse = m + log(s0);  H = lse - s1/s0;  ptl = chosen_logit - lse
__global__ __launch_bounds__(256) void lse_entropy_kernel(
    const float* __restrict__ logits,
    const int*   __restrict__ input_ids,
    float*       __restrict__ out_ptl,   // d_out + 1, length BATCH*TT
    float*       __restrict__ ws_H)      // d_ws, length BATCH*TT
{
    const int row = blockIdx.x;          // 0 .. BATCH*TT-1
    const int b   = row / TT;
    const int t   = row - b * TT;
    const float* rowp = logits + ((size_t)b * SEQ + t) * VOC;
    const float4* row4 = (const float4*)rowp;

    const int tid = threadIdx.x;

    // Load the chosen logit early (independent of the reduction).
    __shared__ float s_chosen;
    if (tid == 0) {
        const int cid = input_ids[b * SEQ + t + 1];
        s_chosen = rowp[cid];
    }

    float m = -FLT_MAX, s0 = 0.f, s1 = 0.f;
    for (int i = tid; i < VOC4; i += 256) {
        const float4 v = row4[i];
        const float m4 = fmaxf(fmaxf(v.x, v.y), fmaxf(v.z, v.w));
        const float mn = fmaxf(m, m4);
        const float c  = __expf(m - mn);     // 0 on first iter (m=-FLT_MAX)
        const float e0 = __expf(v.x - mn);
        const float e1 = __expf(v.y - mn);
        const float e2 = __expf(v.z - mn);
        const float e3 = __expf(v.w - mn);
        s0 = s0 * c + ((e0 + e1) + (e2 + e3));
        s1 = s1 * c + ((e0 * v.x + e1 * v.y) + (e2 * v.z + e3 * v.w));
        m = mn;
    }

    // Wave (64-lane) butterfly reduce of (m, s0, s1).
    #pragma unroll
    for (int off = 32; off > 0; off >>= 1) {
        const float mo  = __shfl_xor(m,  off);
        const float s0o = __shfl_xor(s0, off);
        const float s1o = __shfl_xor(s1, off);
        const float mn = fmaxf(m, mo);
        const float ea = __expf(m  - mn);
        const float eb = __expf(mo - mn);
        s0 = s0 * ea + s0o * eb;
        s1 = s1 * ea + s1o * eb;
        m = mn;
    }

    // Cross-wave combine (4 waves) via LDS.
    __shared__ float sm[4], ss0[4], ss1[4];
    const int wave = tid >> 6;
    const int lane = tid & 63;
    if (lane == 0) { sm[wave] = m; ss0[wave] = s0; ss1[wave] = s1; }
    __syncthreads();
    if (tid == 0) {
        float M = sm[0], S0 = ss0[0], S1 = ss1[0];
        #pragma unroll
        for (int w = 1; w < 4; ++w) {
            const float mn = fmaxf(M, sm[w]);
            const float ea = __expf(M - mn);
            const float eb = __expf(sm[w] - mn);
            S0 = S0 * ea + ss0[w] * eb;
            S1 = S1 * ea + ss1[w] * eb;
            M = mn;
        }
        const float lse = M + __logf(S0);
        out_ptl[row] = s_chosen - lse;       // TEMPERATURE = 1
        ws_H[row]    = lse - S1 / S0;        // token entropy
    }
}

// Kernel 2: single block, wave w handles sample b=w.
// ratio == exp(0) == 1 exactly => per_token_loss == -adv[b];
// loss = -sum_b(adv_b * cnt_b) / sum_b(cnt_b).
// entropy_calc_mask: valid && 4 <= cumsum(valid) <= 100 (inclusive cumsum).
__global__ __launch_bounds__(256) void finalize_kernel(
    const float* __restrict__ ws_H,
    const int*   __restrict__ labels,
    const float* __restrict__ advantages,
    float*       __restrict__ d_out)
{
    const int tid  = threadIdx.x;
    const int b    = tid >> 6;     // wave id == sample id
    const int lane = tid & 63;
    const int t0   = lane * 16;    // 16 tokens per lane (64*16 = 1024 >= 1023)

    // Pass 1: valid bitmask for my 16 tokens (compile-time indices -> no scratch).
    unsigned vmask = 0;
    #pragma unroll
    for (int k = 0; k < 16; ++k) {
        const int t = t0 + k;
        int v = 0;
        if (t < TT) v = (labels[b * SEQ + t + 1] == 1) ? 1 : 0;
        vmask |= (unsigned)v << k;
    }
    const int cnt = __popc(vmask);

    // Inclusive prefix scan of valid counts across the 64 lanes.
    int inc = cnt;
    #pragma unroll
    for (int off = 1; off < 64; off <<= 1) {
        const int up = __shfl_up(inc, off);
        if (lane >= off) inc += up;
    }
    int cum = inc - cnt;  // exclusive prefix: # valid tokens before my chunk

    // Pass 2: accumulate masked entropy sums.
    float sH = 0.f, sMask = 0.f, sHt = 0.f, sCt = 0.f;
    #pragma unroll
    for (int k = 0; k < 16; ++k) {
        const int t = t0 + k;
        if (t < TT && ((vmask >> k) & 1)) {
            const float h = ws_H[b * TT + t];
            cum += 1;
            sH += h; sMask += 1.f;
            if (cum >= 4 && cum <= 100) { sHt += h; sCt += 1.f; }
        }
    }

    // Wave-sum the four accumulators.
    #pragma unroll
    for (int off = 32; off > 0; off >>= 1) {
        sH    += __shfl_xor(sH,    off);
        sMask += __shfl_xor(sMask, off);
        sHt   += __shfl_xor(sHt,   off);
        sCt   += __shfl_xor(sCt,   off);
    }

    __shared__ float sh_cnt[BATCH], sh_adv[BATCH];
    if (lane == 0) {
        d_out[1 + BATCH * TT + b]         = sH / sMask;   // avg_entropy_per_sample
        d_out[1 + BATCH * TT + BATCH + b] = sHt / sCt;    // avg_entropy_trunc
        sh_cnt[b] = sMask;
        sh_adv[b] = advantages[b];
    }
    __syncthreads();
    if (tid == 0) {
        float tot = 0.f, num = 0.f;
        #pragma unroll
        for (int i = 0; i < BATCH; ++i) { tot += sh_cnt[i]; num += sh_adv[i] * sh_cnt[i]; }
        d_out[0] = -num / tot;  // loss
    }
}

extern "C" void kernel_launch(void* const* d_in, const int* in_sizes, int n_in,
                              void* d_out, int out_size, void* d_ws, size_t ws_size,
                              hipStream_t stream) {
    const float* logits     = (const float*)d_in[0];
    const int*   input_ids  = (const int*)d_in[1];
    const int*   labels     = (const int*)d_in[2];
    const float* advantages = (const float*)d_in[3];
    float* out = (float*)d_out;
    float* wsH = (float*)d_ws;   // BATCH*TT floats = 16368 B

    lse_entropy_kernel<<<BATCH * TT, 256, 0, stream>>>(
        logits, input_ids, out + 1, wsH);
    finalize_kernel<<<1, 256, 0, stream>>>(
        wsH, labels, advantages, out);
}

// Round 3
// 87.647 us; speedup vs baseline: 1.1627x; 1.1627x over previous
//
#include <hip/hip_runtime.h>
#include <math.h>
#include <float.h>

// Problem constants (B=4, S=1024, V=32000), T = S-1 = 1023 scored tokens.
#define BATCH 4
#define SEQ   1024
#define TT    1023
#define VOC   32000
#define VOC4  (VOC / 4)   // 8000 float4 per row

typedef float f32x4 __attribute__((ext_vector_type(4)));

// Kernel 1: one block (256 threads) per (b, t) row.
// Online logsumexp + entropy moment in a single streaming pass, with TWO
// independent accumulator streams per thread for ILP / loads-in-flight:
//   m  = running max
//   s0 = sum exp(l - m)
//   s1 = sum exp(l - m) * l
//   lse = m + log(s0);  H = lse - s1/s0;  ptl = chosen_logit - lse
__global__ __launch_bounds__(256) void lse_entropy_kernel(
    const float* __restrict__ logits,
    const int*   __restrict__ input_ids,
    float*       __restrict__ out_ptl,   // d_out + 1, length BATCH*TT
    float*       __restrict__ ws_H)      // d_ws, length BATCH*TT
{
    const int row = blockIdx.x;          // 0 .. BATCH*TT-1
    const int b   = row / TT;
    const int t   = row - b * TT;
    const float* rowp = logits + ((size_t)b * SEQ + t) * VOC;
    const f32x4* row4 = (const f32x4*)rowp;

    const int tid = threadIdx.x;

    // Chosen logit (independent of the reduction) — one lane only.
    __shared__ float s_chosen;
    if (tid == 0) {
        const int cid = input_ids[b * SEQ + t + 1];
        s_chosen = rowp[cid];
    }

    // Two independent online-LSE streams: A covers i = tid + 512k,
    // B covers i = tid + 256 + 512k. Independent dep-chains -> 2x ILP.
    float mA = -FLT_MAX, s0A = 0.f, s1A = 0.f;
    float mB = -FLT_MAX, s0B = 0.f, s1B = 0.f;

    int iA = tid;
    int iB = tid + 256;
    #pragma unroll 1
    for (; iB < VOC4; iA += 512, iB += 512) {
        const f32x4 va = __builtin_nontemporal_load(&row4[iA]);
        const f32x4 vb = __builtin_nontemporal_load(&row4[iB]);

        // stream A
        {
            const float m4 = fmaxf(fmaxf(va.x, va.y), fmaxf(va.z, va.w));
            const float mn = fmaxf(mA, m4);
            const float c  = __expf(mA - mn);     // 0 on first iter
            const float e0 = __expf(va.x - mn);
            const float e1 = __expf(va.y - mn);
            const float e2 = __expf(va.z - mn);
            const float e3 = __expf(va.w - mn);
            s0A = s0A * c + ((e0 + e1) + (e2 + e3));
            s1A = s1A * c + ((e0 * va.x + e1 * va.y) + (e2 * va.z + e3 * va.w));
            mA = mn;
        }
        // stream B
        {
            const float m4 = fmaxf(fmaxf(vb.x, vb.y), fmaxf(vb.z, vb.w));
            const float mn = fmaxf(mB, m4);
            const float c  = __expf(mB - mn);
            const float e0 = __expf(vb.x - mn);
            const float e1 = __expf(vb.y - mn);
            const float e2 = __expf(vb.z - mn);
            const float e3 = __expf(vb.w - mn);
            s0B = s0B * c + ((e0 + e1) + (e2 + e3));
            s1B = s1B * c + ((e0 * vb.x + e1 * vb.y) + (e2 * vb.z + e3 * vb.w));
            mB = mn;
        }
    }
    // A-stream tail (iA may have one more valid iteration).
    if (iA < VOC4) {
        const f32x4 va = __builtin_nontemporal_load(&row4[iA]);
        const float m4 = fmaxf(fmaxf(va.x, va.y), fmaxf(va.z, va.w));
        const float mn = fmaxf(mA, m4);
        const float c  = __expf(mA - mn);
        const float e0 = __expf(va.x - mn);
        const float e1 = __expf(va.y - mn);
        const float e2 = __expf(va.z - mn);
        const float e3 = __expf(va.w - mn);
        s0A = s0A * c + ((e0 + e1) + (e2 + e3));
        s1A = s1A * c + ((e0 * va.x + e1 * va.y) + (e2 * va.z + e3 * va.w));
        mA = mn;
    }

    // Merge streams B into A.
    {
        const float mn = fmaxf(mA, mB);
        const float ea = __expf(mA - mn);
        const float eb = __expf(mB - mn);
        s0A = s0A * ea + s0B * eb;
        s1A = s1A * ea + s1B * eb;
        mA = mn;
    }
    float m = mA, s0 = s0A, s1 = s1A;

    // Wave (64-lane) butterfly reduce of (m, s0, s1).
    #pragma unroll
    for (int off = 32; off > 0; off >>= 1) {
        const float mo  = __shfl_xor(m,  off);
        const float s0o = __shfl_xor(s0, off);
        const float s1o = __shfl_xor(s1, off);
        const float mn = fmaxf(m, mo);
        const float ea = __expf(m  - mn);
        const float eb = __expf(mo - mn);
        s0 = s0 * ea + s0o * eb;
        s1 = s1 * ea + s1o * eb;
        m = mn;
    }

    // Cross-wave combine (4 waves) via LDS.
    __shared__ float sm[4], ss0[4], ss1[4];
    const int wave = tid >> 6;
    const int lane = tid & 63;
    if (lane == 0) { sm[wave] = m; ss0[wave] = s0; ss1[wave] = s1; }
    __syncthreads();
    if (tid == 0) {
        float M = sm[0], S0 = ss0[0], S1 = ss1[0];
        #pragma unroll
        for (int w = 1; w < 4; ++w) {
            const float mn = fmaxf(M, sm[w]);
            const float ea = __expf(M - mn);
            const float eb = __expf(sm[w] - mn);
            S0 = S0 * ea + ss0[w] * eb;
            S1 = S1 * ea + ss1[w] * eb;
            M = mn;
        }
        const float lse = M + __logf(S0);
        out_ptl[row] = s_chosen - lse;       // TEMPERATURE = 1
        ws_H[row]    = lse - S1 / S0;        // token entropy
    }
}

// Kernel 2: single block, wave w handles sample b=w.
// ratio == exp(0) == 1 exactly => per_token_loss == -adv[b];
// loss = -sum_b(adv_b * cnt_b) / sum_b(cnt_b).
// entropy_calc_mask: valid && 4 <= cumsum(valid) <= 100 (inclusive cumsum).
__global__ __launch_bounds__(256) void finalize_kernel(
    const float* __restrict__ ws_H,
    const int*   __restrict__ labels,
    const float* __restrict__ advantages,
    float*       __restrict__ d_out)
{
    const int tid  = threadIdx.x;
    const int b    = tid >> 6;     // wave id == sample id
    const int lane = tid & 63;
    const int t0   = lane * 16;    // 16 tokens per lane (64*16 = 1024 >= 1023)

    // Pass 1: valid bitmask for my 16 tokens.
    unsigned vmask = 0;
    #pragma unroll
    for (int k = 0; k < 16; ++k) {
        const int t = t0 + k;
        int v = 0;
        if (t < TT) v = (labels[b * SEQ + t + 1] == 1) ? 1 : 0;
        vmask |= (unsigned)v << k;
    }
    const int cnt = __popc(vmask);

    // Inclusive prefix scan of valid counts across the 64 lanes.
    int inc = cnt;
    #pragma unroll
    for (int off = 1; off < 64; off <<= 1) {
        const int up = __shfl_up(inc, off);
        if (lane >= off) inc += up;
    }
    int cum = inc - cnt;  // exclusive prefix: # valid tokens before my chunk

    // Pass 2: accumulate masked entropy sums.
    float sH = 0.f, sMask = 0.f, sHt = 0.f, sCt = 0.f;
    #pragma unroll
    for (int k = 0; k < 16; ++k) {
        const int t = t0 + k;
        if (t < TT && ((vmask >> k) & 1)) {
            const float h = ws_H[b * TT + t];
            cum += 1;
            sH += h; sMask += 1.f;
            if (cum >= 4 && cum <= 100) { sHt += h; sCt += 1.f; }
        }
    }

    // Wave-sum the four accumulators.
    #pragma unroll
    for (int off = 32; off > 0; off >>= 1) {
        sH    += __shfl_xor(sH,    off);
        sMask += __shfl_xor(sMask, off);
        sHt   += __shfl_xor(sHt,   off);
        sCt   += __shfl_xor(sCt,   off);
    }

    __shared__ float sh_cnt[BATCH], sh_adv[BATCH];
    if (lane == 0) {
        d_out[1 + BATCH * TT + b]         = sH / sMask;   // avg_entropy_per_sample
        d_out[1 + BATCH * TT + BATCH + b] = sHt / sCt;    // avg_entropy_trunc
        sh_cnt[b] = sMask;
        sh_adv[b] = advantages[b];
    }
    __syncthreads();
    if (tid == 0) {
        float tot = 0.f, num = 0.f;
        #pragma unroll
        for (int i = 0; i < BATCH; ++i) { tot += sh_cnt[i]; num += sh_adv[i] * sh_cnt[i]; }
        d_out[0] = -num / tot;  // loss
    }
}

extern "C" void kernel_launch(void* const* d_in, const int* in_sizes, int n_in,
                              void* d_out, int out_size, void* d_ws, size_t ws_size,
                              hipStream_t stream) {
    const float* logits     = (const float*)d_in[0];
    const int*   input_ids  = (const int*)d_in[1];
    const int*   labels     = (const int*)d_in[2];
    const float* advantages = (const float*)d_in[3];
    float* out = (float*)d_out;
    float* wsH = (float*)d_ws;   // BATCH*TT floats = 16368 B

    lse_entropy_kernel<<<BATCH * TT, 256, 0, stream>>>(
        logits, input_ids, out + 1, wsH);
    finalize_kernel<<<1, 256, 0, stream>>>(
        wsH, labels, advantages, out);
}